// Round 2
// baseline (265.089 us; speedup 1.0000x reference)
//
#include <hip/hip_runtime.h>

// ST-GCN fused block for MI355X (gfx950).  FP32 I/O (reference dtype), bf16
// internally at MFMA operand boundaries only.
// Pipeline: kpre -> kwin -> kmain -> kstats -> kapply (all on `stream`).

typedef unsigned short ushort_t;
typedef __attribute__((ext_vector_type(8))) short short8;   // 8 x bf16 MFMA frag
typedef __attribute__((ext_vector_type(4))) float f32x4;
typedef __attribute__((ext_vector_type(4))) unsigned short us4;

#define N_  4
#define CI_ 64
#define CO_ 64
#define L_  1024
#define V_  25
#define P_  3
#define KS_ 9
#define NLV 102400.0f   // N_*L_*V_  (BN population count per channel)

__device__ __forceinline__ float b2f(ushort_t u) {
  union { float f; unsigned int i; } c; c.i = ((unsigned int)u) << 16; return c.f;
}
__device__ __forceinline__ ushort_t f2b(float f) {
  union { float f; unsigned int i; } c; c.f = f;
  unsigned int u = c.i;
  u += 0x7fffu + ((u >> 16) & 1u);      // round-to-nearest-even
  return (ushort_t)(u >> 16);
}

// ---------------------------------------------------------------------------
// kpre (fp32 in): build A2^T (bf16), bias table (f32), Wb (bf16), zero stats.
//   a2raw[w][p*32+v] = A[p][v][w]*E[p][v][w]  (v<25,w<25 else 0)   [32][96]
//   biastab[c][w]    = sum_p b[p*64+c] * sum_v Ae[p][v][w]         [64][32] f32
//   wb[k][c]         = bf16(conv_w[k][c])                          [192][64]
__global__ __launch_bounds__(256) void kpre(
    const float* __restrict__ A, const float* __restrict__ E,
    const float* __restrict__ cb, const float* __restrict__ W,
    ushort_t* __restrict__ a2raw, float* __restrict__ biastab,
    ushort_t* __restrict__ wb, float* __restrict__ stats)
{
  const int tid = threadIdx.x;
  __shared__ float colA[P_ * 32];
  if (tid < P_ * 32) {
    int p = tid >> 5, w = tid & 31;
    float s = 0.f;
    if (w < V_)
      for (int v = 0; v < V_; ++v) {
        int idx = (p * V_ + v) * V_ + w;
        s += A[idx] * E[idx];
      }
    colA[tid] = s;
  }
  for (int e = tid; e < 32 * 96; e += 256) {
    int w = e / 96, k = e - w * 96;
    int p = k >> 5, v = k & 31;
    float val = 0.f;
    if (w < V_ && v < V_) {
      int idx = (p * V_ + v) * V_ + w;
      val = A[idx] * E[idx];
    }
    a2raw[e] = f2b(val);
  }
  for (int e = tid; e < 192 * 64; e += 256) wb[e] = f2b(W[e]);
  __syncthreads();
  for (int e = tid; e < 64 * 32; e += 256) {
    int c = e >> 5, w = e & 31;
    float s = 0.f;
    for (int p = 0; p < P_; ++p) s += cb[p * 64 + c] * colA[p * 32 + w];
    biastab[e] = s;
  }
  for (int e = tid; e < 128; e += 256) stats[e] = 0.f;
}

// ---------------------------------------------------------------------------
// kwin: causal 9-wide window-sum along l (Toeplitz), fp32 in -> bf16 out.
// block = ((n*64+ci)*4 + chunk), chunk = 256 l's, LDS staging with 8-row halo.
__global__ __launch_bounds__(256) void kwin(
    const float* __restrict__ x, ushort_t* __restrict__ xs)
{
  __shared__ float buf[264 * V_];             // 26.4 KB
  const int b = blockIdx.x;
  const int slab = b >> 2;                    // n*64+ci
  const int chunk = b & 3;
  const int base = slab * (L_ * V_);
  const int l0 = chunk * 256;
  const int off = base + (l0 - 8) * V_;       // halo start (may precede slab)
  for (int e = threadIdx.x; e < 264 * V_; e += 256) {
    int gi = off + e;
    buf[e] = (gi >= base) ? x[gi] : 0.f;      // zero-fill l<0 halo
  }
  __syncthreads();
  for (int e = threadIdx.x; e < 256 * V_; e += 256) {
    float s = 0.f;
#pragma unroll
    for (int j = 0; j < KS_; ++j) s += buf[e + V_ * j];
    xs[base + l0 * V_ + e] = f2b(s);
  }
}

// ---------------------------------------------------------------------------
// kmain: per-(n,l) block.  stage1: t1[k=192][v=32] = Wb[192x64] @ Xs[64x32]
//        stage2: z[c=64][w=32] = t1c[64x96] @ A2[96x32]; + cnt(l)*bias; -> zb
// zb layout: [n][l][w(25)][c(64)] bf16 (c innermost -> coalesced stats pass)
__global__ __launch_bounds__(256) void kmain(
    const ushort_t* __restrict__ xs,      // [n][ci][l][v] (windowed, bf16)
    const ushort_t* __restrict__ Wb,      // [192][64] bf16
    const ushort_t* __restrict__ a2,      // [32][96]  bf16
    const float*    __restrict__ biastab, // [64][32]  f32
    ushort_t*       __restrict__ zb)
{
  const int l = blockIdx.x;
  const int n = blockIdx.y;
  const int tid  = threadIdx.x;
  const int lane = tid & 63;
  const int wv   = tid >> 6;        // 4 waves
  const int m16  = lane & 15;
  const int quad = lane >> 4;

  __shared__ __align__(16) ushort_t Xt[32 * 72];    // [v][ci], stride 72
  __shared__ __align__(16) ushort_t A2t[32 * 104];  // [w][K=96], stride 104
  __shared__ __align__(16) ushort_t T1[64 * 104];   // [c][K=96], stride 104

  // fill Xt[v][ci] from xs[n][ci][l][v]  (transpose)
  for (int e = tid; e < CI_ * V_; e += 256) {
    int ci = e / V_, v = e - ci * V_;
    Xt[v * 72 + ci] = xs[((n * CI_ + ci) * L_ + l) * V_ + v];
  }
  for (int e = tid; e < 7 * 72; e += 256) Xt[25 * 72 + e] = 0;  // pad rows v=25..31
  for (int e = tid; e < 32 * 96; e += 256) {
    int r = e / 96, k = e - r * 96;
    A2t[r * 104 + k] = a2[e];
  }
  __syncthreads();

  // ---- stage 1: 12 MFMA per wave (3 mt x 2 nt x 2 ks) ----
  f32x4 acc1[3][2];
#pragma unroll
  for (int i = 0; i < 3; ++i)
#pragma unroll
    for (int j = 0; j < 2; ++j) acc1[i][j] = (f32x4){0.f, 0.f, 0.f, 0.f};

#pragma unroll
  for (int i = 0; i < 3; ++i) {
    const int mt = wv * 3 + i;
    const ushort_t* wrow = Wb + (mt * 16 + m16) * 64 + quad * 8;  // A-frag from global (L2-hot)
#pragma unroll
    for (int ks = 0; ks < 2; ++ks) {
      short8 af = *(const short8*)(wrow + ks * 32);
#pragma unroll
      for (int nt = 0; nt < 2; ++nt) {
        short8 bf = *(const short8*)(&Xt[(nt * 16 + m16) * 72 + ks * 32 + quad * 8]);
        acc1[i][nt] = __builtin_amdgcn_mfma_f32_16x16x32_bf16(af, bf, acc1[i][nt], 0, 0, 0);
      }
    }
  }
  // repack t1 -> T1[c][p*32+v]  (D: row = quad*4+r, col = m16)
#pragma unroll
  for (int i = 0; i < 3; ++i) {
    const int mt = wv * 3 + i;
#pragma unroll
    for (int nt = 0; nt < 2; ++nt) {
      const int col = nt * 16 + m16;
#pragma unroll
      for (int r = 0; r < 4; ++r) {
        int k = mt * 16 + quad * 4 + r;              // k = p*64 + c
        T1[(k & 63) * 104 + (k >> 6) * 32 + col] = f2b(acc1[i][nt][r]);
      }
    }
  }
  __syncthreads();

  // ---- stage 2: 6 MFMA per wave (1 mt x 2 nt x 3 ks) ----
  f32x4 acc2[2];
  acc2[0] = (f32x4){0.f, 0.f, 0.f, 0.f};
  acc2[1] = (f32x4){0.f, 0.f, 0.f, 0.f};
  const int mt2 = wv;
#pragma unroll
  for (int ks = 0; ks < 3; ++ks) {
    short8 af = *(const short8*)(&T1[(mt2 * 16 + m16) * 104 + ks * 32 + quad * 8]);
#pragma unroll
    for (int nt = 0; nt < 2; ++nt) {
      short8 bf = *(const short8*)(&A2t[(nt * 16 + m16) * 104 + ks * 32 + quad * 8]);
      acc2[nt] = __builtin_amdgcn_mfma_f32_16x16x32_bf16(af, bf, acc2[nt], 0, 0, 0);
    }
  }

  // epilogue: + cnt(l)*bias, store 4 consecutive c as one 8B write
  const float cnt = (float)(l + 1 < KS_ ? l + 1 : KS_);
#pragma unroll
  for (int nt = 0; nt < 2; ++nt) {
    const int w = nt * 16 + m16;
    if (w < V_) {
      const int cbase = mt2 * 16 + quad * 4;
      us4 pack;
#pragma unroll
      for (int r = 0; r < 4; ++r) {
        float zv = acc2[nt][r] + cnt * biastab[(cbase + r) * 32 + w];
        pack[r] = f2b(zv);
      }
      *(us4*)(&zb[(((n * L_ + l) * V_ + w) << 6) + cbase]) = pack;
    }
  }
}

// ---------------------------------------------------------------------------
// kstats: per-channel sum / sumsq over zb.  block = (l-chunk of 64, n).
__global__ __launch_bounds__(256) void kstats(
    const ushort_t* __restrict__ zb, float* __restrict__ stats)
{
  const int n = blockIdx.y, chunk = blockIdx.x;
  const int tid = threadIdx.x;
  const int c = tid & 63, j = tid >> 6;
  const long base = (long)((n * L_ + chunk * 64) * V_) * 64;
  float s1 = 0.f, s2 = 0.f;
  for (int idx = j; idx < 64 * V_; idx += 4) {
    float z = b2f(zb[base + (long)idx * 64 + c]);
    s1 += z; s2 += z * z;
  }
  __shared__ float r1[256], r2[256];
  r1[tid] = s1; r2[tid] = s2;
  __syncthreads();
  if (tid < 64) {
    float a = r1[tid] + r1[tid + 64] + r1[tid + 128] + r1[tid + 192];
    float b = r2[tid] + r2[tid + 64] + r2[tid + 128] + r2[tid + 192];
    atomicAdd(&stats[tid], a);
    atomicAdd(&stats[64 + tid], b);
  }
}

// ---------------------------------------------------------------------------
// kapply: out[n,c,l,v] = relu(relu((z-mean)*rstd*g+b) + x).  fp32 residual+out.
__global__ __launch_bounds__(256) void kapply(
    const ushort_t* __restrict__ zb, const float* __restrict__ x,
    const float* __restrict__ stats,
    const float* __restrict__ gamma, const float* __restrict__ beta,
    float* __restrict__ out)
{
  const int n = blockIdx.y, chunk = blockIdx.x;   // 16 l's per block
  const int tid = threadIdx.x;
  __shared__ ushort_t zl[400 * 66];               // [(l*25+v)][c], stride 66
  __shared__ float sc[64], sh[64];
  const long zbase = (long)((n * L_ + chunk * 16) * V_) * 64;
  for (int e = tid; e < 25600; e += 256)
    zl[(e >> 6) * 66 + (e & 63)] = zb[zbase + e];
  if (tid < 64) {
    const float inv = 1.0f / NLV;
    float mean = stats[tid] * inv;
    float var  = stats[64 + tid] * inv - mean * mean;
    float rstd = rsqrtf(var + 1e-5f);
    float g = gamma[tid];
    sc[tid] = rstd * g;
    sh[tid] = beta[tid] - mean * rstd * g;
  }
  __syncthreads();
  for (int e = tid; e < 25600; e += 256) {
    int c = e / 400, rr = e - c * 400;            // rr = l*25+v within chunk
    float z = b2f(zl[rr * 66 + c]);
    float y = fmaxf(z * sc[c] + sh[c], 0.f);
    long xi = ((long)(n * 64 + c) * L_ + chunk * 16) * V_ + rr;
    float o = fmaxf(y + x[xi], 0.f);
    out[xi] = o;
  }
}

// ---------------------------------------------------------------------------
extern "C" void kernel_launch(void* const* d_in, const int* in_sizes, int n_in,
                              void* d_out, int out_size, void* d_ws, size_t ws_size,
                              hipStream_t stream)
{
  const float* x     = (const float*)d_in[0];
  const float* A     = (const float*)d_in[1];
  const float* E     = (const float*)d_in[2];
  const float* W     = (const float*)d_in[3];
  const float* cb    = (const float*)d_in[4];
  const float* gamma = (const float*)d_in[5];
  const float* beta  = (const float*)d_in[6];
  float* out = (float*)d_out;

  char* ws = (char*)d_ws;
  const size_t XS_OFF   = 0;                       // 13,107,200 B (bf16 xs)
  const size_t ZB_OFF   = 13107200;                // 13,107,200 B (bf16 zb)
  const size_t WB_OFF   = 26214400;                // 24,576 B (bf16 Wb)
  const size_t A2_OFF   = 26214400 + 32768;        // 6,144 B
  const size_t BIAS_OFF = 26214400 + 49152;        // 8,192 B
  const size_t STAT_OFF = 26214400 + 65536;        // 512 B
  ushort_t* xs      = (ushort_t*)(ws + XS_OFF);
  ushort_t* zb      = (ushort_t*)(ws + ZB_OFF);
  ushort_t* wb      = (ushort_t*)(ws + WB_OFF);
  ushort_t* a2      = (ushort_t*)(ws + A2_OFF);
  float*    biastab = (float*)(ws + BIAS_OFF);
  float*    stats   = (float*)(ws + STAT_OFF);

  kpre  <<<1, 256, 0, stream>>>(A, E, cb, W, a2, biastab, wb, stats);
  kwin  <<<N_ * CI_ * 4, 256, 0, stream>>>(x, xs);
  kmain <<<dim3(L_, N_), 256, 0, stream>>>(xs, wb, a2, biastab, zb);
  kstats<<<dim3(16, N_), 256, 0, stream>>>(zb, stats);
  kapply<<<dim3(64, N_), 256, 0, stream>>>(zb, x, stats, gamma, beta, out);
}

// Round 3
// 170.842 us; speedup vs baseline: 1.5517x; 1.5517x over previous
//
#include <hip/hip_runtime.h>

// ST-GCN fused block for MI355X (gfx950).  FP32 I/O (reference dtype), bf16
// internally at MFMA operand boundaries only.
// Pipeline: kpre -> kwin -> kmain -> kstats -> kapply (all on `stream`).

typedef unsigned short ushort_t;
typedef __attribute__((ext_vector_type(8))) short short8;   // 8 x bf16 MFMA frag
typedef __attribute__((ext_vector_type(4))) float f32x4;
typedef __attribute__((ext_vector_type(4))) unsigned short us4;
typedef __attribute__((ext_vector_type(4))) unsigned int ui4;

#define N_  4
#define CI_ 64
#define CO_ 64
#define L_  1024
#define V_  25
#define P_  3
#define KS_ 9
#define NLV 102400.0f   // N_*L_*V_  (BN population count per channel)

__device__ __forceinline__ float b2f(ushort_t u) {
  union { float f; unsigned int i; } c; c.i = ((unsigned int)u) << 16; return c.f;
}
__device__ __forceinline__ ushort_t f2b(float f) {
  union { float f; unsigned int i; } c; c.f = f;
  unsigned int u = c.i;
  u += 0x7fffu + ((u >> 16) & 1u);      // round-to-nearest-even
  return (ushort_t)(u >> 16);
}

// ---------------------------------------------------------------------------
// kpre (fp32 in): build A2^T (bf16), bias table (f32), Wb (bf16), zero stats.
__global__ __launch_bounds__(256) void kpre(
    const float* __restrict__ A, const float* __restrict__ E,
    const float* __restrict__ cb, const float* __restrict__ W,
    ushort_t* __restrict__ a2raw, float* __restrict__ biastab,
    ushort_t* __restrict__ wb, float* __restrict__ stats)
{
  const int tid = threadIdx.x;
  __shared__ float colA[P_ * 32];
  if (tid < P_ * 32) {
    int p = tid >> 5, w = tid & 31;
    float s = 0.f;
    if (w < V_)
      for (int v = 0; v < V_; ++v) {
        int idx = (p * V_ + v) * V_ + w;
        s += A[idx] * E[idx];
      }
    colA[tid] = s;
  }
  for (int e = tid; e < 32 * 96; e += 256) {
    int w = e / 96, k = e - w * 96;
    int p = k >> 5, v = k & 31;
    float val = 0.f;
    if (w < V_ && v < V_) {
      int idx = (p * V_ + v) * V_ + w;
      val = A[idx] * E[idx];
    }
    a2raw[e] = f2b(val);
  }
  for (int e = tid; e < 192 * 64; e += 256) wb[e] = f2b(W[e]);
  __syncthreads();
  for (int e = tid; e < 64 * 32; e += 256) {
    int c = e >> 5, w = e & 31;
    float s = 0.f;
    for (int p = 0; p < P_; ++p) s += cb[p * 64 + c] * colA[p * 32 + w];
    biastab[e] = s;
  }
  for (int e = tid; e < 128; e += 256) stats[e] = 0.f;
}

// ---------------------------------------------------------------------------
// kwin: causal 9-wide window-sum along l (Toeplitz), fp32 in -> bf16 out.
__global__ __launch_bounds__(256) void kwin(
    const float* __restrict__ x, ushort_t* __restrict__ xs)
{
  __shared__ float buf[264 * V_];             // 26.4 KB
  const int b = blockIdx.x;
  const int slab = b >> 2;                    // n*64+ci
  const int chunk = b & 3;
  const int base = slab * (L_ * V_);
  const int l0 = chunk * 256;
  const int off = base + (l0 - 8) * V_;       // halo start (may precede slab)
  for (int e = threadIdx.x; e < 264 * V_; e += 256) {
    int gi = off + e;
    buf[e] = (gi >= base) ? x[gi] : 0.f;      // zero-fill l<0 halo
  }
  __syncthreads();
  for (int e = threadIdx.x; e < 256 * V_; e += 256) {
    float s = 0.f;
#pragma unroll
    for (int j = 0; j < KS_; ++j) s += buf[e + V_ * j];
    xs[base + l0 * V_ + e] = f2b(s);
  }
}

// ---------------------------------------------------------------------------
// kmain: per-(n,l) block.  stage1: t1[k=192][v=32] = Wb[192x64] @ Xs[64x32]
//        stage2: z[c=64][w=32] = t1c[64x96] @ A2[96x32]; + cnt(l)*bias; -> zb
// zb layout: [n][l][w(25)][c(64)] bf16 (c innermost -> coalesced stats pass)
__global__ __launch_bounds__(256) void kmain(
    const ushort_t* __restrict__ xs,      // [n][ci][l][v] (windowed, bf16)
    const ushort_t* __restrict__ Wb,      // [192][64] bf16
    const ushort_t* __restrict__ a2,      // [32][96]  bf16
    const float*    __restrict__ biastab, // [64][32]  f32
    ushort_t*       __restrict__ zb)
{
  const int l = blockIdx.x;
  const int n = blockIdx.y;
  const int tid  = threadIdx.x;
  const int lane = tid & 63;
  const int wv   = tid >> 6;        // 4 waves
  const int m16  = lane & 15;
  const int quad = lane >> 4;

  __shared__ __align__(16) ushort_t Xt[32 * 72];    // [v][ci], stride 72
  __shared__ __align__(16) ushort_t A2t[32 * 104];  // [w][K=96], stride 104
  __shared__ __align__(16) ushort_t T1[64 * 104];   // [c][K=96], stride 104

  for (int e = tid; e < CI_ * V_; e += 256) {
    int ci = e / V_, v = e - ci * V_;
    Xt[v * 72 + ci] = xs[((n * CI_ + ci) * L_ + l) * V_ + v];
  }
  for (int e = tid; e < 7 * 72; e += 256) Xt[25 * 72 + e] = 0;  // pad rows v=25..31
  for (int e = tid; e < 32 * 96; e += 256) {
    int r = e / 96, k = e - r * 96;
    A2t[r * 104 + k] = a2[e];
  }
  __syncthreads();

  // ---- stage 1: 12 MFMA per wave (3 mt x 2 nt x 2 ks) ----
  f32x4 acc1[3][2];
#pragma unroll
  for (int i = 0; i < 3; ++i)
#pragma unroll
    for (int j = 0; j < 2; ++j) acc1[i][j] = (f32x4){0.f, 0.f, 0.f, 0.f};

#pragma unroll
  for (int i = 0; i < 3; ++i) {
    const int mt = wv * 3 + i;
    const ushort_t* wrow = Wb + (mt * 16 + m16) * 64 + quad * 8;  // A-frag from global (L2-hot)
#pragma unroll
    for (int ks = 0; ks < 2; ++ks) {
      short8 af = *(const short8*)(wrow + ks * 32);
#pragma unroll
      for (int nt = 0; nt < 2; ++nt) {
        short8 bf = *(const short8*)(&Xt[(nt * 16 + m16) * 72 + ks * 32 + quad * 8]);
        acc1[i][nt] = __builtin_amdgcn_mfma_f32_16x16x32_bf16(af, bf, acc1[i][nt], 0, 0, 0);
      }
    }
  }
  // repack t1 -> T1[c][p*32+v]  (D: row = quad*4+r, col = m16)
#pragma unroll
  for (int i = 0; i < 3; ++i) {
    const int mt = wv * 3 + i;
#pragma unroll
    for (int nt = 0; nt < 2; ++nt) {
      const int col = nt * 16 + m16;
#pragma unroll
      for (int r = 0; r < 4; ++r) {
        int k = mt * 16 + quad * 4 + r;              // k = p*64 + c
        T1[(k & 63) * 104 + (k >> 6) * 32 + col] = f2b(acc1[i][nt][r]);
      }
    }
  }
  __syncthreads();

  // ---- stage 2: 6 MFMA per wave (1 mt x 2 nt x 3 ks) ----
  f32x4 acc2[2];
  acc2[0] = (f32x4){0.f, 0.f, 0.f, 0.f};
  acc2[1] = (f32x4){0.f, 0.f, 0.f, 0.f};
  const int mt2 = wv;
#pragma unroll
  for (int ks = 0; ks < 3; ++ks) {
    short8 af = *(const short8*)(&T1[(mt2 * 16 + m16) * 104 + ks * 32 + quad * 8]);
#pragma unroll
    for (int nt = 0; nt < 2; ++nt) {
      short8 bf = *(const short8*)(&A2t[(nt * 16 + m16) * 104 + ks * 32 + quad * 8]);
      acc2[nt] = __builtin_amdgcn_mfma_f32_16x16x32_bf16(af, bf, acc2[nt], 0, 0, 0);
    }
  }

  // epilogue: + cnt(l)*bias, store 4 consecutive c as one 8B write
  const float cnt = (float)(l + 1 < KS_ ? l + 1 : KS_);
#pragma unroll
  for (int nt = 0; nt < 2; ++nt) {
    const int w = nt * 16 + m16;
    if (w < V_) {
      const int cbase = mt2 * 16 + quad * 4;
      us4 pack;
#pragma unroll
      for (int r = 0; r < 4; ++r) {
        float zv = acc2[nt][r] + cnt * biastab[(cbase + r) * 32 + w];
        pack[r] = f2b(zv);
      }
      *(us4*)(&zb[(((n * L_ + l) * V_ + w) << 6) + cbase]) = pack;
    }
  }
}

// ---------------------------------------------------------------------------
// kstats: per-channel sum/sumsq over zb (flat [102400 rows][64 c]).
// 320 blocks x 320 rows; each thread: 10 x 16B loads (8 channels),
// butterfly-shuffle across the 8 lanes sharing a channel group, LDS combine,
// 128 atomics/block.
__global__ __launch_bounds__(256) void kstats(
    const ushort_t* __restrict__ zb, float* __restrict__ stats)
{
  const int tid  = threadIdx.x;
  const int lane = tid & 63, wv = tid >> 6;
  const int cg = tid & 7;          // channel group: channels cg*8 .. cg*8+7
  const int r0 = tid >> 3;         // 0..31
  const long base = (long)blockIdx.x * 320 * 64;
  float s1[8], s2[8];
#pragma unroll
  for (int k = 0; k < 8; ++k) { s1[k] = 0.f; s2[k] = 0.f; }
  for (int r = r0; r < 320; r += 32) {
    ui4 d = *(const ui4*)(zb + base + (long)r * 64 + cg * 8);
#pragma unroll
    for (int j = 0; j < 4; ++j) {
      union { float f; unsigned int i; } lo, hi;
      lo.i = d[j] << 16;
      hi.i = d[j] & 0xffff0000u;
      s1[2 * j]     += lo.f;  s2[2 * j]     += lo.f * lo.f;
      s1[2 * j + 1] += hi.f;  s2[2 * j + 1] += hi.f * hi.f;
    }
  }
#pragma unroll
  for (int off = 8; off <= 32; off <<= 1) {
#pragma unroll
    for (int k = 0; k < 8; ++k) {
      s1[k] += __shfl_xor(s1[k], off, 64);
      s2[k] += __shfl_xor(s2[k], off, 64);
    }
  }
  __shared__ float red[4][8][8][2];
  if (lane < 8) {                  // lane == cg for these lanes
#pragma unroll
    for (int k = 0; k < 8; ++k) {
      red[wv][lane][k][0] = s1[k];
      red[wv][lane][k][1] = s2[k];
    }
  }
  __syncthreads();
  if (tid < 64) {                  // c = (tid>>3)*8 + (tid&7) = tid
    int g = tid >> 3, k = tid & 7;
    float a = red[0][g][k][0] + red[1][g][k][0] + red[2][g][k][0] + red[3][g][k][0];
    float b = red[0][g][k][1] + red[1][g][k][1] + red[2][g][k][1] + red[3][g][k][1];
    atomicAdd(&stats[tid], a);
    atomicAdd(&stats[64 + tid], b);
  }
}

// ---------------------------------------------------------------------------
// kapply: out[n,c,l,v] = relu(relu((z-mean)*rstd*g+b) + x).  fp32 residual+out.
// 8 l's per block -> 512 blocks; zb staged to LDS with 4B loads.
__global__ __launch_bounds__(256) void kapply(
    const ushort_t* __restrict__ zb, const float* __restrict__ x,
    const float* __restrict__ stats,
    const float* __restrict__ gamma, const float* __restrict__ beta,
    float* __restrict__ out)
{
  const int n = blockIdx.y, chunk = blockIdx.x;   // 8 l's per block
  const int tid = threadIdx.x;
  __shared__ ushort_t zl[200 * 66];               // [(l*25+v)][c], stride 66
  __shared__ float sc[64], sh[64];
  const long zbase = (long)((n * L_ + chunk * 8) * V_) * 64;
  for (int pe = tid; pe < 6400; pe += 256) {      // pairs of bf16
    unsigned int d = ((const unsigned int*)(zb + zbase))[pe];
    int row = pe >> 5;                            // (2pe)>>6
    int col = (pe & 31) * 2;
    *(unsigned int*)(&zl[row * 66 + col]) = d;
  }
  if (tid < 64) {
    const float inv = 1.0f / NLV;
    float mean = stats[tid] * inv;
    float var  = stats[64 + tid] * inv - mean * mean;
    float rstd = rsqrtf(var + 1e-5f);
    float g = gamma[tid];
    sc[tid] = rstd * g;
    sh[tid] = beta[tid] - mean * rstd * g;
  }
  __syncthreads();
  for (int e = tid; e < 12800; e += 256) {
    int c = e / 200, rr = e - c * 200;            // rr = l*25+v within chunk
    float z = b2f(zl[rr * 66 + c]);
    float y = fmaxf(z * sc[c] + sh[c], 0.f);
    long xi = ((long)(n * 64 + c) * L_ + chunk * 8) * V_ + rr;
    float o = fmaxf(y + x[xi], 0.f);
    out[xi] = o;
  }
}

// ---------------------------------------------------------------------------
extern "C" void kernel_launch(void* const* d_in, const int* in_sizes, int n_in,
                              void* d_out, int out_size, void* d_ws, size_t ws_size,
                              hipStream_t stream)
{
  const float* x     = (const float*)d_in[0];
  const float* A     = (const float*)d_in[1];
  const float* E     = (const float*)d_in[2];
  const float* W     = (const float*)d_in[3];
  const float* cb    = (const float*)d_in[4];
  const float* gamma = (const float*)d_in[5];
  const float* beta  = (const float*)d_in[6];
  float* out = (float*)d_out;

  char* ws = (char*)d_ws;
  const size_t XS_OFF   = 0;                       // 13,107,200 B (bf16 xs)
  const size_t ZB_OFF   = 13107200;                // 13,107,200 B (bf16 zb)
  const size_t WB_OFF   = 26214400;                // 24,576 B (bf16 Wb)
  const size_t A2_OFF   = 26214400 + 32768;        // 6,144 B
  const size_t BIAS_OFF = 26214400 + 49152;        // 8,192 B
  const size_t STAT_OFF = 26214400 + 65536;        // 512 B
  ushort_t* xs      = (ushort_t*)(ws + XS_OFF);
  ushort_t* zb      = (ushort_t*)(ws + ZB_OFF);
  ushort_t* wb      = (ushort_t*)(ws + WB_OFF);
  ushort_t* a2      = (ushort_t*)(ws + A2_OFF);
  float*    biastab = (float*)(ws + BIAS_OFF);
  float*    stats   = (float*)(ws + STAT_OFF);

  kpre  <<<1, 256, 0, stream>>>(A, E, cb, W, a2, biastab, wb, stats);
  kwin  <<<N_ * CI_ * 4, 256, 0, stream>>>(x, xs);
  kmain <<<dim3(L_, N_), 256, 0, stream>>>(xs, wb, a2, biastab, zb);
  kstats<<<320, 256, 0, stream>>>(zb, stats);
  kapply<<<dim3(128, N_), 256, 0, stream>>>(zb, x, stats, gamma, beta, out);
}

// Round 4
// 160.326 us; speedup vs baseline: 1.6534x; 1.0656x over previous
//
#include <hip/hip_runtime.h>

// ST-GCN fused block for MI355X (gfx950).  FP32 I/O, bf16 at MFMA boundaries.
// Pipeline: kpre -> kwin -> kmain -> kstats -> kapply (all on `stream`).
// xs layout: [n][l][v][ci] (ci contiguous -> vector staging in kmain).
// zb layout: [n][l][w][c]  (c contiguous -> coalesced kstats/kapply).

typedef unsigned short ushort_t;
typedef __attribute__((ext_vector_type(8))) short short8;   // 8 x bf16 MFMA frag
typedef __attribute__((ext_vector_type(4))) float f32x4;
typedef __attribute__((ext_vector_type(4))) unsigned short us4;
typedef __attribute__((ext_vector_type(8))) unsigned short us8;
typedef __attribute__((ext_vector_type(4))) unsigned int ui4;

#define N_  4
#define CI_ 64
#define CO_ 64
#define L_  1024
#define V_  25
#define P_  3
#define KS_ 9
#define NLV 102400.0f   // N_*L_*V_  (BN population count per channel)

__device__ __forceinline__ float b2f(ushort_t u) {
  union { float f; unsigned int i; } c; c.i = ((unsigned int)u) << 16; return c.f;
}
__device__ __forceinline__ ushort_t f2b(float f) {
  union { float f; unsigned int i; } c; c.f = f;
  unsigned int u = c.i;
  u += 0x7fffu + ((u >> 16) & 1u);      // round-to-nearest-even
  return (ushort_t)(u >> 16);
}

// ---------------------------------------------------------------------------
// kpre (fp32 in): A2^T (bf16), bias table [w][c] (f32), Wb (bf16), zero stats.
//   a2raw[w][p*32+v] = A[p][v][w]*E[p][v][w]  (v<25,w<25 else 0)   [32][96]
//   biastab[w][c]    = sum_p b[p*64+c] * sum_v Ae[p][v][w]         [32][64] f32
__global__ __launch_bounds__(256) void kpre(
    const float* __restrict__ A, const float* __restrict__ E,
    const float* __restrict__ cb, const float* __restrict__ W,
    ushort_t* __restrict__ a2raw, float* __restrict__ biastab,
    ushort_t* __restrict__ wb, float* __restrict__ stats)
{
  const int tid = threadIdx.x;
  __shared__ float colA[P_ * 32];
  if (tid < P_ * 32) {
    int p = tid >> 5, w = tid & 31;
    float s = 0.f;
    if (w < V_)
      for (int v = 0; v < V_; ++v) {
        int idx = (p * V_ + v) * V_ + w;
        s += A[idx] * E[idx];
      }
    colA[tid] = s;
  }
  for (int e = tid; e < 32 * 96; e += 256) {
    int w = e / 96, k = e - w * 96;
    int p = k >> 5, v = k & 31;
    float val = 0.f;
    if (w < V_ && v < V_) {
      int idx = (p * V_ + v) * V_ + w;
      val = A[idx] * E[idx];
    }
    a2raw[e] = f2b(val);
  }
  for (int e = tid; e < 192 * 64; e += 256) wb[e] = f2b(W[e]);
  __syncthreads();
  for (int e = tid; e < 32 * 64; e += 256) {
    int w = e >> 6, c = e & 63;
    float s = 0.f;
    for (int p = 0; p < P_; ++p) s += cb[p * 64 + c] * colA[p * 32 + w];
    biastab[e] = s;
  }
  for (int e = tid; e < 128; e += 256) stats[e] = 0.f;
}

// ---------------------------------------------------------------------------
// kwin: causal 9-wide window-sum along l, fp32 in -> bf16 xs[n][l][v][ci].
// block = (chunk of 8 l's, n).  Stage x[n][ci][l0-8..l0+8)[v] as bf16 in LDS
// tile [ci][402] (stride 402: odd dword step -> conflict-free column reads).
__global__ __launch_bounds__(256) void kwin(
    const float* __restrict__ x, ushort_t* __restrict__ xs)
{
  __shared__ ushort_t tile[64 * 402];           // 51.5 KB
  const int chunk = blockIdx.x;                 // 0..127
  const int n = blockIdx.y;
  const int tid = threadIdx.x;
  const int l0 = chunk * 8;
  const long xn = (long)n * CI_ * L_ * V_;
  // stage: 64 ci x 400 f32 -> bf16; float4 chunks: 6400
  for (int m = tid; m < 6400; m += 256) {
    int ci = m / 100;
    int j4 = (m - ci * 100) * 4;                // 0..396
    f32x4 d;
    if (chunk == 0 && j4 < 200) {
      d = (f32x4){0.f, 0.f, 0.f, 0.f};          // l < 0 halo
    } else {
      d = *(const f32x4*)(x + xn + (long)ci * (L_ * V_) + (l0 - 8) * V_ + j4);
    }
    ushort_t* dst = &tile[ci * 402 + j4];
    dst[0] = f2b(d[0]); dst[1] = f2b(d[1]); dst[2] = f2b(d[2]); dst[3] = f2b(d[3]);
  }
  __syncthreads();
  const long xsbase = ((long)n * L_ + l0) * (V_ * 64);
  for (int e = tid; e < 8 * 1600; e += 256) {   // lane = ci -> coalesced write
    int l_ = e / 1600, r = e - l_ * 1600;
    int v = r >> 6, ci = r & 63;
    int b0 = ci * 402 + (8 + l_) * 25 + v;
    float s = 0.f;
#pragma unroll
    for (int d = 0; d < 9; ++d) s += b2f(tile[b0 - d * 25]);
    xs[xsbase + e] = f2b(s);
  }
}

// ---------------------------------------------------------------------------
// kmain: per-(n, 2 l's) block.
//   stage1: t1[k=192][2l x 32v] = Wb[192x64] @ Xs[64 x 64cols]
//   stage2: z[c=64][w=32] per l = T1c[64x96] @ A2[96x32]; + cnt(l)*bias
__global__ __launch_bounds__(256) void kmain(
    const ushort_t* __restrict__ xs,      // [n][l][v][ci] bf16
    const ushort_t* __restrict__ Wb,      // [192][64] bf16
    const ushort_t* __restrict__ a2,      // [32][96]  bf16
    const float*    __restrict__ biastab, // [32 w][64 c] f32
    ushort_t*       __restrict__ zb)
{
  const int lb = blockIdx.x;            // 2 l's per block
  const int n  = blockIdx.y;
  const int tid = threadIdx.x, lane = tid & 63, wv = tid >> 6;
  const int m16 = lane & 15, quad = lane >> 4;

  __shared__ __align__(16) ushort_t XT[2 * 32 * 72];   // [l_][v][ci], stride 72
  __shared__ __align__(16) ushort_t A2t[32 * 104];     // [w][K=96],  stride 104
  __shared__ __align__(16) ushort_t T1[2 * 64 * 104];  // [l_][c][K=96]

  // stage XT: 3200 contiguous bf16 -> 400 us8 chunks (vector, coalesced)
  {
    const ushort_t* src = xs + ((long)n * L_ + 2 * lb) * 1600;
    for (int m = tid; m < 400; m += 256) {
      int l_ = m / 200, mr = m - l_ * 200;
      int v = mr >> 3, sub = mr & 7;
      *(us8*)(&XT[l_ * 2304 + v * 72 + sub * 8]) = *(const us8*)(src + m * 8);
    }
    if (tid < 252) {                    // zero v=25..31 pad rows (both l_)
      ((unsigned int*)XT)[900 + tid] = 0;
      ((unsigned int*)XT)[900 + 1152 + tid] = 0;
    }
    for (int m = tid; m < 384; m += 256) {     // A2t: 3072 bf16 -> us8
      int r = m / 12, k8 = m - r * 12;
      *(us8*)(&A2t[r * 104 + k8 * 8]) = *(const us8*)(a2 + m * 8);
    }
  }
  __syncthreads();

  // ---- stage 1: 24 MFMA per wave (3 mt x 4 nt x 2 ks) ----
  short8 bfr[4][2];
#pragma unroll
  for (int nt = 0; nt < 4; ++nt)
#pragma unroll
    for (int ks = 0; ks < 2; ++ks)
      bfr[nt][ks] = *(const short8*)(
          &XT[(nt >> 1) * 2304 + ((nt & 1) * 16 + m16) * 72 + ks * 32 + quad * 8]);

  f32x4 acc1[3][4];
#pragma unroll
  for (int i = 0; i < 3; ++i)
#pragma unroll
    for (int j = 0; j < 4; ++j) acc1[i][j] = (f32x4){0.f, 0.f, 0.f, 0.f};

#pragma unroll
  for (int i = 0; i < 3; ++i) {
    const int mt = wv * 3 + i;
    const ushort_t* wrow = Wb + (mt * 16 + m16) * 64 + quad * 8;
    short8 af0 = *(const short8*)(wrow);
    short8 af1 = *(const short8*)(wrow + 32);
#pragma unroll
    for (int nt = 0; nt < 4; ++nt) {
      acc1[i][nt] = __builtin_amdgcn_mfma_f32_16x16x32_bf16(af0, bfr[nt][0], acc1[i][nt], 0, 0, 0);
      acc1[i][nt] = __builtin_amdgcn_mfma_f32_16x16x32_bf16(af1, bfr[nt][1], acc1[i][nt], 0, 0, 0);
    }
  }
  // repack t1 -> T1[l_][c][p*32+v]  (D: row = quad*4+r, col = m16)
#pragma unroll
  for (int i = 0; i < 3; ++i) {
    const int mt = wv * 3 + i;
#pragma unroll
    for (int nt = 0; nt < 4; ++nt) {
      const int l_ = nt >> 1;
      const int col = (nt & 1) * 16 + m16;
#pragma unroll
      for (int r = 0; r < 4; ++r) {
        int k = mt * 16 + quad * 4 + r;          // k = p*64 + c
        T1[l_ * 6656 + (k & 63) * 104 + (k >> 6) * 32 + col] = f2b(acc1[i][nt][r]);
      }
    }
  }
  __syncthreads();

  // ---- stage 2: 12 MFMA per wave (2 l_ x 2 nt x 3 ks) ----
  short8 bfr2[2][3];
#pragma unroll
  for (int nt = 0; nt < 2; ++nt)
#pragma unroll
    for (int ks = 0; ks < 3; ++ks)
      bfr2[nt][ks] = *(const short8*)(&A2t[(nt * 16 + m16) * 104 + ks * 32 + quad * 8]);

  f32x4 acc2[2][2];
#pragma unroll
  for (int l_ = 0; l_ < 2; ++l_)
#pragma unroll
    for (int nt = 0; nt < 2; ++nt) acc2[l_][nt] = (f32x4){0.f, 0.f, 0.f, 0.f};

#pragma unroll
  for (int l_ = 0; l_ < 2; ++l_) {
#pragma unroll
    for (int ks = 0; ks < 3; ++ks) {
      short8 af = *(const short8*)(&T1[l_ * 6656 + (wv * 16 + m16) * 104 + ks * 32 + quad * 8]);
      acc2[l_][0] = __builtin_amdgcn_mfma_f32_16x16x32_bf16(af, bfr2[0][ks], acc2[l_][0], 0, 0, 0);
      acc2[l_][1] = __builtin_amdgcn_mfma_f32_16x16x32_bf16(af, bfr2[1][ks], acc2[l_][1], 0, 0, 0);
    }
  }

  // epilogue: + cnt(l)*bias (float4), store us4
  const int cbase = wv * 16 + quad * 4;
#pragma unroll
  for (int l_ = 0; l_ < 2; ++l_) {
    const int l = 2 * lb + l_;
    const float cnt = (float)(l + 1 < KS_ ? l + 1 : KS_);
#pragma unroll
    for (int nt = 0; nt < 2; ++nt) {
      const int w = nt * 16 + m16;
      if (w < V_) {
        f32x4 bias = *(const f32x4*)(biastab + w * 64 + cbase);
        us4 pack;
#pragma unroll
        for (int r = 0; r < 4; ++r) pack[r] = f2b(acc2[l_][nt][r] + cnt * bias[r]);
        *(us4*)(&zb[(((long)(n * L_ + l) * V_ + w) << 6) + cbase]) = pack;
      }
    }
  }
}

// ---------------------------------------------------------------------------
// kstats: per-channel sum/sumsq over zb (flat [102400 rows][64 c]).
// 320 blocks x 320 rows; 16B loads, butterfly shuffle, 128 atomics/block.
__global__ __launch_bounds__(256) void kstats(
    const ushort_t* __restrict__ zb, float* __restrict__ stats)
{
  const int tid  = threadIdx.x;
  const int lane = tid & 63, wv = tid >> 6;
  const int cg = tid & 7;          // channel group: channels cg*8 .. cg*8+7
  const int r0 = tid >> 3;         // 0..31
  const long base = (long)blockIdx.x * 320 * 64;
  float s1[8], s2[8];
#pragma unroll
  for (int k = 0; k < 8; ++k) { s1[k] = 0.f; s2[k] = 0.f; }
  for (int r = r0; r < 320; r += 32) {
    ui4 d = *(const ui4*)(zb + base + (long)r * 64 + cg * 8);
#pragma unroll
    for (int j = 0; j < 4; ++j) {
      union { float f; unsigned int i; } lo, hi;
      lo.i = d[j] << 16;
      hi.i = d[j] & 0xffff0000u;
      s1[2 * j]     += lo.f;  s2[2 * j]     += lo.f * lo.f;
      s1[2 * j + 1] += hi.f;  s2[2 * j + 1] += hi.f * hi.f;
    }
  }
#pragma unroll
  for (int off = 8; off <= 32; off <<= 1) {
#pragma unroll
    for (int k = 0; k < 8; ++k) {
      s1[k] += __shfl_xor(s1[k], off, 64);
      s2[k] += __shfl_xor(s2[k], off, 64);
    }
  }
  __shared__ float red[4][8][8][2];
  if (lane < 8) {
#pragma unroll
    for (int k = 0; k < 8; ++k) {
      red[wv][lane][k][0] = s1[k];
      red[wv][lane][k][1] = s2[k];
    }
  }
  __syncthreads();
  if (tid < 64) {
    int g = tid >> 3, k = tid & 7;
    float a = red[0][g][k][0] + red[1][g][k][0] + red[2][g][k][0] + red[3][g][k][0];
    float b = red[0][g][k][1] + red[1][g][k][1] + red[2][g][k][1] + red[3][g][k][1];
    atomicAdd(&stats[tid], a);
    atomicAdd(&stats[64 + tid], b);
  }
}

// ---------------------------------------------------------------------------
// kapply: out[n,c,l,v] = relu(relu((z-mean)*rstd*g+b) + x).  4 l's per block.
// zl [rr(100)][c] stride 66 -> both LDS phases ~conflict-free.
__global__ __launch_bounds__(256) void kapply(
    const ushort_t* __restrict__ zb, const float* __restrict__ x,
    const float* __restrict__ stats,
    const float* __restrict__ gamma, const float* __restrict__ beta,
    float* __restrict__ out)
{
  const int n = blockIdx.y, chunk = blockIdx.x;   // 4 l's per block
  const int tid = threadIdx.x;
  __shared__ ushort_t zl[100 * 66];               // 13.2 KB
  __shared__ float sc[64], sh[64];
  const long zbase = (long)((n * L_ + chunk * 4) * V_) * 64;   // 6400 elems
  for (int m = tid; m < 3200; m += 256) {         // u32 = 2 bf16
    int rr = m >> 5, c2 = (m & 31) * 2;
    *(unsigned int*)(&zl[rr * 66 + c2]) = ((const unsigned int*)(zb + zbase))[m];
  }
  if (tid < 64) {
    const float inv = 1.0f / NLV;
    float mean = stats[tid] * inv;
    float var  = stats[64 + tid] * inv - mean * mean;
    float rstd = rsqrtf(var + 1e-5f);
    float g = gamma[tid];
    sc[tid] = rstd * g;
    sh[tid] = beta[tid] - mean * rstd * g;
  }
  __syncthreads();
  for (int e = tid; e < 6400; e += 256) {
    int c = e / 100, rr = e - c * 100;            // rr = l*25+v within chunk
    float z = b2f(zl[rr * 66 + c]);
    float y = fmaxf(z * sc[c] + sh[c], 0.f);
    long xi = ((long)(n * 64 + c) * L_ + chunk * 4) * V_ + rr;
    float o = fmaxf(y + x[xi], 0.f);
    out[xi] = o;
  }
}

// ---------------------------------------------------------------------------
extern "C" void kernel_launch(void* const* d_in, const int* in_sizes, int n_in,
                              void* d_out, int out_size, void* d_ws, size_t ws_size,
                              hipStream_t stream)
{
  const float* x     = (const float*)d_in[0];
  const float* A     = (const float*)d_in[1];
  const float* E     = (const float*)d_in[2];
  const float* W     = (const float*)d_in[3];
  const float* cb    = (const float*)d_in[4];
  const float* gamma = (const float*)d_in[5];
  const float* beta  = (const float*)d_in[6];
  float* out = (float*)d_out;

  char* ws = (char*)d_ws;
  const size_t XS_OFF   = 0;                       // 13,107,200 B (bf16 xs)
  const size_t ZB_OFF   = 13107200;                // 13,107,200 B (bf16 zb)
  const size_t WB_OFF   = 26214400;                // 24,576 B (bf16 Wb)
  const size_t A2_OFF   = 26214400 + 32768;        // 6,144 B
  const size_t BIAS_OFF = 26214400 + 49152;        // 8,192 B
  const size_t STAT_OFF = 26214400 + 65536;        // 512 B
  ushort_t* xs      = (ushort_t*)(ws + XS_OFF);
  ushort_t* zb      = (ushort_t*)(ws + ZB_OFF);
  ushort_t* wb      = (ushort_t*)(ws + WB_OFF);
  ushort_t* a2      = (ushort_t*)(ws + A2_OFF);
  float*    biastab = (float*)(ws + BIAS_OFF);
  float*    stats   = (float*)(ws + STAT_OFF);

  kpre  <<<1, 256, 0, stream>>>(A, E, cb, W, a2, biastab, wb, stats);
  kwin  <<<dim3(128, N_), 256, 0, stream>>>(x, xs);
  kmain <<<dim3(512, N_), 256, 0, stream>>>(xs, wb, a2, biastab, zb);
  kstats<<<320, 256, 0, stream>>>(zb, stats);
  kapply<<<dim3(256, N_), 256, 0, stream>>>(zb, x, stats, gamma, beta, out);
}